// Round 1
// baseline (173.668 us; speedup 1.0000x reference)
//
#include <hip/hip_runtime.h>

// SiamFC cross-correlation: out[n,0,oh,ow] = sum_{c,i,j} x[n,c,oh+i,ow+j] * z[n,c,i,j]
// n=256, c=256, z=6x6, x=26x26, out=21x21.

#define C_ALL 256
#define HZ 6
#define WZ 6
#define HX 26
#define WX 26
#define OH 21
#define OW 21
#define CHUNK 4      // channels staged per barrier round
#define HALF_C 128   // channels per block (2 blocks per sample)

__global__ __launch_bounds__(256, 2)
void siamfc_xcorr(const float* __restrict__ z, const float* __restrict__ x,
                  float* __restrict__ out) {
    __shared__ float xs[CHUNK * HX * WX + 64];  // +64 pad: q=10 lanes read 1 row past end

    const int tid = threadIdx.x;
    const int bid = blockIdx.x;
    const int n    = bid >> 1;
    const int half = bid & 1;
    const int cbase0 = half * HALF_C;

    // Each active thread owns a vertical pair of outputs: rows (2q, 2q+1), col ow.
    const int q  = tid / OW;          // 0..11 for tid<252
    const int ow = tid % OW;
    const bool active = (tid < 11 * OW);   // 231 threads
    const int r0 = 2 * q;

    float acc0 = 0.f, acc1 = 0.f;

    const float4* xg4base = (const float4*)(x + (size_t)n * C_ALL * (HX * WX));
    const float*  zbase   = z + (size_t)n * C_ALL * (HZ * WZ);

    for (int chunk = 0; chunk < HALF_C / CHUNK; ++chunk) {
        const int cbase = cbase0 + chunk * CHUNK;
        __syncthreads();
        // Stage CHUNK contiguous channels of x: CHUNK*676 floats = 676 float4.
        const float4* src = xg4base + (size_t)cbase * (HX * WX / 4);
        float4* dst = (float4*)xs;
        for (int v = tid; v < CHUNK * (HX * WX / 4); v += 256) {
            dst[v] = src[v];
        }
        __syncthreads();

        if (active) {
            #pragma unroll
            for (int cc = 0; cc < CHUNK; ++cc) {
                const float* xc = xs + cc * (HX * WX);
                const float* zc = zbase + (size_t)(cbase + cc) * (HZ * WZ);
                // z address is block-uniform -> compiler scalarizes to s_load.
                float zz[HZ * WZ];
                #pragma unroll
                for (int k = 0; k < HZ * WZ; ++k) zz[k] = zc[k];
                // 7 rows x 6 cols of x cover both outputs (rows r0..r0+6).
                float xv[HZ + 1][WZ];
                #pragma unroll
                for (int i = 0; i < HZ + 1; ++i)
                    #pragma unroll
                    for (int j = 0; j < WZ; ++j)
                        xv[i][j] = xc[(r0 + i) * WX + ow + j];
                #pragma unroll
                for (int i = 0; i < HZ; ++i)
                    #pragma unroll
                    for (int j = 0; j < WZ; ++j) {
                        acc0 = fmaf(zz[i * WZ + j], xv[i][j],     acc0);
                        acc1 = fmaf(zz[i * WZ + j], xv[i + 1][j], acc1);
                    }
            }
        }
    }

    if (active) {
        float* o = out + (size_t)n * (OH * OW);
        atomicAdd(&o[r0 * OW + ow], acc0);
        if (q < 10) atomicAdd(&o[(r0 + 1) * OW + ow], acc1);
    }
}

extern "C" void kernel_launch(void* const* d_in, const int* in_sizes, int n_in,
                              void* d_out, int out_size, void* d_ws, size_t ws_size,
                              hipStream_t stream) {
    const float* z = (const float*)d_in[0];
    const float* x = (const float*)d_in[1];
    float* out = (float*)d_out;
    // Zero accumulation target (harness poisons d_out once before timing).
    hipMemsetAsync(d_out, 0, (size_t)out_size * sizeof(float), stream);
    siamfc_xcorr<<<dim3(2 * 256), dim3(256), 0, stream>>>(z, x, out);
}

// Round 2
// 89.682 us; speedup vs baseline: 1.9365x; 1.9365x over previous
//
#include <hip/hip_runtime.h>

// SiamFC cross-correlation: out[n,0,oh,ow] = sum_{c,i,j} x[n,c,oh+i,ow+j] * z[n,c,i,j]
// n=256, c=256, z=6x6, x=26x26, out=21x21.
//
// Structure: grid = 256 samples x 8 channel-splits (32 ch each), block = 192 threads.
// Per round, 8 channels staged in LDS (rows padded 26->28 floats for 16B-aligned
// ds_read_b128). Thread (cc, r) computes output row r over channel cc of each
// round, holding 21 accumulators; per x-row read (7x b128) it does 126 FMAs.

#define C_ALL 256
#define HZ 6
#define WZ 6
#define HX 26
#define WX 26
#define OH 21
#define OW 21
#define PADW 28
#define CCON 8                    // concurrent channels per round
#define CH_PER_BLOCK 32           // 8 splits per sample
#define ROUNDS (CH_PER_BLOCK / CCON)
#define NTHREADS 192
#define ACTIVE (CCON * OH)        // 168
#define RED_STRIDE 456            // 441 outputs + 15 pad (456%32==8 -> cc groups offset banks)

__global__ __launch_bounds__(NTHREADS, 4)
void siamfc_xcorr(const float* __restrict__ z, const float* __restrict__ x,
                  float* __restrict__ out) {
    __shared__ float xs[CCON * HX * PADW];   // 5824 floats = 23296 B (also reused for reduction)
    __shared__ float zs[CCON * HZ * WZ];     // 288 floats

    const int tid = threadIdx.x;
    const int bid = blockIdx.x;
    const int n     = bid >> 3;
    const int split = bid & 7;
    const int cbase0 = split * CH_PER_BLOCK;

    const int cc = tid / OH;        // 0..7 (for tid < 168)
    const int r  = tid - cc * OH;   // 0..20
    const bool active = (tid < ACTIVE);

    float acc[OW];
    #pragma unroll
    for (int o = 0; o < OW; ++o) acc[o] = 0.f;

    const float2* xsrc2_base = (const float2*)(x + (size_t)n * C_ALL * (HX * WX));
    const float4* zsrc4_base = (const float4*)(z + (size_t)n * C_ALL * (HZ * WZ));

    for (int round = 0; round < ROUNDS; ++round) {
        const int cbase = cbase0 + round * CCON;
        __syncthreads();
        // ---- stage x: 8 ch x 338 float2 (contiguous in global), pad rows 26->28 in LDS
        {
            const float2* src = xsrc2_base + (size_t)cbase * (HX * WX / 2);
            for (int u = tid; u < CCON * HX * (WX / 2); u += NTHREADS) {
                float2 v = src[u];
                int ch  = u / (HX * WX / 2);            // /338
                int rem = u - ch * (HX * WX / 2);
                int row = rem / (WX / 2);               // /13
                int seg = rem - row * (WX / 2);
                ((float2*)xs)[ch * (HX * PADW / 2) + row * (PADW / 2) + seg] = v;
            }
            // ---- stage z: 8 ch x 9 float4, linear copy
            const float4* zsrc = zsrc4_base + (size_t)cbase * (HZ * WZ / 4);
            for (int e = tid; e < CCON * (HZ * WZ / 4); e += NTHREADS) {
                ((float4*)zs)[e] = zsrc[e];
            }
        }
        __syncthreads();

        if (active) {
            const float* xc = xs + cc * (HX * PADW);
            const float* zc = zs + cc * (HZ * WZ);
            #pragma unroll
            for (int i = 0; i < HZ; ++i) {
                // x row (r+i): 7 aligned b128 reads -> 28 floats in regs
                const float4* rp = (const float4*)(xc + (r + i) * PADW);
                float xr[PADW];
                #pragma unroll
                for (int k = 0; k < 7; ++k) {
                    float4 f = rp[k];
                    xr[4 * k + 0] = f.x; xr[4 * k + 1] = f.y;
                    xr[4 * k + 2] = f.z; xr[4 * k + 3] = f.w;
                }
                // z row i: 3 aligned b64 broadcast reads
                const float2* zrow = (const float2*)(zc + i * WZ);
                float2 za = zrow[0], zb = zrow[1], zd = zrow[2];
                float zv[WZ] = {za.x, za.y, zb.x, zb.y, zd.x, zd.y};
                #pragma unroll
                for (int j = 0; j < WZ; ++j)
                    #pragma unroll
                    for (int o = 0; o < OW; ++o)
                        acc[o] = fmaf(zv[j], xr[o + j], acc[o]);
            }
        }
    }

    // ---- reduce across the 8 cc groups (reuse xs), then 8-way global atomic
    __syncthreads();
    if (active) {
        float* red = xs + cc * RED_STRIDE + r * OW;
        #pragma unroll
        for (int o = 0; o < OW; ++o) red[o] = acc[o];
    }
    __syncthreads();
    float* og = out + (size_t)n * (OH * OW);
    for (int o = tid; o < OH * OW; o += NTHREADS) {
        float s = 0.f;
        #pragma unroll
        for (int c2 = 0; c2 < CCON; ++c2) s += xs[c2 * RED_STRIDE + o];
        atomicAdd(&og[o], s);
    }
}

extern "C" void kernel_launch(void* const* d_in, const int* in_sizes, int n_in,
                              void* d_out, int out_size, void* d_ws, size_t ws_size,
                              hipStream_t stream) {
    const float* z = (const float*)d_in[0];
    const float* x = (const float*)d_in[1];
    float* out = (float*)d_out;
    hipMemsetAsync(d_out, 0, (size_t)out_size * sizeof(float), stream);
    siamfc_xcorr<<<dim3(256 * 8), dim3(NTHREADS), 0, stream>>>(z, x, out);
}